// Round 1
// baseline (216.285 us; speedup 1.0000x reference)
//
#include <hip/hip_runtime.h>

#define BB 16
#define AA 3
#define CC 80
#define NT 256

__device__ __forceinline__ float sigf(float x){ return 1.f/(1.f+expf(-x)); }
__device__ __forceinline__ float clogf_(float p){ return fmaxf(logf(p), -100.f); }

// 256-thread block reduction + single atomicAdd(out, sum*scale)
__device__ __forceinline__ void block_reduce_atomic(float v, float* out, float scale){
    #pragma unroll
    for (int o = 32; o > 0; o >>= 1) v += __shfl_down(v, o, 64);
    __shared__ float wsum[4];
    int lane = threadIdx.x & 63;
    int wid  = threadIdx.x >> 6;
    if (lane == 0) wsum[wid] = v;
    __syncthreads();
    if (threadIdx.x == 0) {
        float s = wsum[0] + wsum[1] + wsum[2] + wsum[3];
        atomicAdd(out, s * scale);
    }
}

__global__ void zero_kernel(float* out){ out[0] = 0.f; }

// One thread per cell across all 3 scales; reads only channel 4.
// grid = 403200/256 = 1575 blocks exactly.
__global__ void noobj_kernel(const float* __restrict__ p0, const float* __restrict__ p1,
                             const float* __restrict__ p2, float* __restrict__ out){
    const int n0 = BB*AA*80*80;   // 307200
    const int n1 = BB*AA*40*40;   // 76800
    int i = blockIdx.x * 256 + threadIdx.x;
    const float* p; int cell;
    if (i < n0)            { p = p0; cell = i; }
    else if (i < n0 + n1)  { p = p1; cell = i - n0; }
    else                   { p = p2; cell = i - n0 - n1; }
    float x = p[(long)cell * 85 + 4];
    float term = clogf_(1.f - sigf(x));   // log(1 - sigmoid), clamped at -100
    block_reduce_atomic(term, out, -0.5f);
}

// 3 blocks (one per scale) x 256 threads (one per target).
__global__ void targets_kernel(const float* __restrict__ p0, const float* __restrict__ p1,
                               const float* __restrict__ p2, const float* __restrict__ anchors,
                               const float* __restrict__ targets, float* __restrict__ out){
    int s = blockIdx.x;
    int g = (s == 0) ? 80 : ((s == 1) ? 40 : 20);
    const float* pred = (s == 0) ? p0 : ((s == 1) ? p1 : p2);
    float stride = 640.f / (float)g;
    int t = threadIdx.x;

    float x = targets[t*6 + 2] * (float)g;
    float y = targets[t*6 + 3] * (float)g;
    float w = targets[t*6 + 4] * 640.f;
    float h = targets[t*6 + 5] * 640.f;
    int bi = (int)targets[t*6 + 0];
    int ci = (int)targets[t*6 + 1];

    bool valid = (x >= 0.f) && (y >= 0.f) && (x <= (float)(g-1)) && (y <= (float)(g-1));
    int gx = (int)floorf(x), gy = (int)floorf(y);

    // best anchor: argmax IoU, first max wins (strict >) to match jnp.argmax
    float best_iou = -1.f, saw = 1.f, sah = 1.f; int best = 0;
    #pragma unroll
    for (int a = 0; a < 3; a++){
        float aw = anchors[s*6 + a*2 + 0] * stride;
        float ah = anchors[s*6 + a*2 + 1] * stride;
        float inter = fminf(w, aw) * fminf(h, ah);
        float iou = inter / (w*h + aw*ah - inter + 1e-16f);
        if (iou > best_iou){ best_iou = iou; best = a; saw = aw; sah = ah; }
    }

    // scatter dedup: last target writing a cell wins (XLA scatter-set ordering)
    __shared__ int skey[NT];
    int key = valid ? (((bi*AA + best)*g + gy)*g + gx) : -1;
    skey[t] = key;
    __syncthreads();
    bool owner = valid;
    if (valid){
        for (int t2 = t + 1; t2 < NT; t2++){
            if (skey[t2] == key){ owner = false; break; }
        }
    }

    float acc = 0.f;
    if (owner){
        const float* pc = pred + (long)key * 85;
        float txv = x - (float)gx;
        float tyv = y - (float)gy;
        float twv = logf(w/saw + 1e-16f);
        float thv = logf(h/sah + 1e-16f);
        float px = sigf(pc[0]); acc += (px - txv)*(px - txv);
        float py = sigf(pc[1]); acc += (py - tyv)*(py - tyv);
        float dw = pc[2] - twv; acc += dw*dw;
        float dh = pc[3] - thv; acc += dh*dh;
        float pobj = sigf(pc[4]);
        acc += -clogf_(pobj);              // obj term
        acc += 0.5f*clogf_(1.f - pobj);    // cancel noobj_kernel's count for this obj cell
        for (int c = 0; c < CC; c++){
            float pcv = sigf(pc[5 + c]);
            acc += -((c == ci) ? clogf_(pcv) : clogf_(1.f - pcv));
        }
    }
    block_reduce_atomic(acc, out, 1.f);
}

extern "C" void kernel_launch(void* const* d_in, const int* in_sizes, int n_in,
                              void* d_out, int out_size, void* d_ws, size_t ws_size,
                              hipStream_t stream) {
    const float* p0      = (const float*)d_in[0];
    const float* p1      = (const float*)d_in[1];
    const float* p2      = (const float*)d_in[2];
    const float* anchors = (const float*)d_in[3];
    const float* targets = (const float*)d_in[4];
    float* out = (float*)d_out;

    zero_kernel<<<1, 1, 0, stream>>>(out);
    noobj_kernel<<<1575, 256, 0, stream>>>(p0, p1, p2, out);
    targets_kernel<<<3, 256, 0, stream>>>(p0, p1, p2, anchors, targets, out);
}

// Round 2
// 184.986 us; speedup vs baseline: 1.1692x; 1.1692x over previous
//
#include <hip/hip_runtime.h>

#define BB 16
#define AA 3
#define CC 80
#define NT 256

#define NOOBJ_BLOCKS 256
#define TOTAL_BLOCKS (NOOBJ_BLOCKS + 3)   // +3 target blocks (one per scale)
#define NCELL (BB*AA*(80*80 + 40*40 + 20*20))   // 403200

__device__ __forceinline__ float sigf(float x){ return 1.f/(1.f+expf(-x)); }
__device__ __forceinline__ float clogf_(float p){ return fmaxf(logf(p), -100.f); }

// block(256) reduce -> returns total to thread 0 (valid only on thread 0)
__device__ __forceinline__ float block_reduce(float v){
    #pragma unroll
    for (int o = 32; o > 0; o >>= 1) v += __shfl_down(v, o, 64);
    __shared__ float wsum[4];
    int lane = threadIdx.x & 63;
    int wid  = threadIdx.x >> 6;
    if (lane == 0) wsum[wid] = v;
    __syncthreads();
    return wsum[0] + wsum[1] + wsum[2] + wsum[3];
}

// Fused kernel: blocks [0,256) -> noobj partials (grid-stride over all cells,
// channel 4 only); blocks [256,259) -> per-scale target terms.
// Each block stores ONE partial to ws[blockIdx.x] — no atomics anywhere.
__global__ void yolo_main_kernel(const float* __restrict__ p0, const float* __restrict__ p1,
                                 const float* __restrict__ p2, const float* __restrict__ anchors,
                                 const float* __restrict__ targets, float* __restrict__ ws){
    const int n0 = BB*AA*80*80;   // 307200
    const int n1 = BB*AA*40*40;   // 76800

    float partial = 0.f;

    if (blockIdx.x < NOOBJ_BLOCKS) {
        // ---- noobj path: sum -0.5 * clog(1 - sigmoid(ch4)) over all cells ----
        float acc = 0.f;
        for (int i = blockIdx.x * 256 + threadIdx.x; i < NCELL; i += NOOBJ_BLOCKS * 256) {
            const float* p; int cell;
            if (i < n0)            { p = p0; cell = i; }
            else if (i < n0 + n1)  { p = p1; cell = i - n0; }
            else                   { p = p2; cell = i - n0 - n1; }
            float x = p[(long)cell * 85 + 4];
            // log(1 - sigmoid(x)) = -softplus(x); clamp at -100 like torch BCE
            acc += fmaxf(-log1pf(expf(x)), -100.f);
        }
        partial = block_reduce(acc) * -0.5f;   // valid on thread 0
    } else {
        // ---- targets path: one block per scale, one thread per target ----
        int s = blockIdx.x - NOOBJ_BLOCKS;
        int g = (s == 0) ? 80 : ((s == 1) ? 40 : 20);
        const float* pred = (s == 0) ? p0 : ((s == 1) ? p1 : p2);
        float stride = 640.f / (float)g;
        int t = threadIdx.x;

        float x = targets[t*6 + 2] * (float)g;
        float y = targets[t*6 + 3] * (float)g;
        float w = targets[t*6 + 4] * 640.f;
        float h = targets[t*6 + 5] * 640.f;
        int bi = (int)targets[t*6 + 0];
        int ci = (int)targets[t*6 + 1];

        bool valid = (x >= 0.f) && (y >= 0.f) && (x <= (float)(g-1)) && (y <= (float)(g-1));
        int gx = (int)floorf(x), gy = (int)floorf(y);

        // argmax IoU over 3 anchors, first max wins (matches jnp.argmax)
        float best_iou = -1.f, saw = 1.f, sah = 1.f;
        #pragma unroll
        for (int a = 0; a < 3; a++){
            float aw = anchors[s*6 + a*2 + 0] * stride;
            float ah = anchors[s*6 + a*2 + 1] * stride;
            float inter = fminf(w, aw) * fminf(h, ah);
            float iou = inter / (w*h + aw*ah - inter + 1e-16f);
            if (iou > best_iou){ best_iou = iou; saw = aw; sah = ah; }
        }

        // last-write-wins dedup (XLA scatter-set ordering)
        __shared__ int skey[NT];
        int key = valid ? (((bi*AA + ((saw==anchors[s*6+0]*stride && sah==anchors[s*6+1]*stride) ? 0
                                     : (saw==anchors[s*6+2]*stride && sah==anchors[s*6+3]*stride) ? 1 : 2))*g + gy)*g + gx)
                        : -1;
        // NOTE: recompute best index robustly instead of float-compare:
        {
            float bi2 = -1.f; int besti = 0;
            #pragma unroll
            for (int a = 0; a < 3; a++){
                float aw = anchors[s*6 + a*2 + 0] * stride;
                float ah = anchors[s*6 + a*2 + 1] * stride;
                float inter = fminf(w, aw) * fminf(h, ah);
                float iou = inter / (w*h + aw*ah - inter + 1e-16f);
                if (iou > bi2){ bi2 = iou; besti = a; }
            }
            key = valid ? (((bi*AA + besti)*g + gy)*g + gx) : -1;
        }
        skey[t] = key;
        __syncthreads();
        bool owner = valid;
        if (valid){
            for (int t2 = t + 1; t2 < NT; t2++){
                if (skey[t2] == key){ owner = false; break; }
            }
        }

        float acc = 0.f;
        if (owner){
            const float* pc = pred + (long)key * 85;
            float txv = x - (float)gx;
            float tyv = y - (float)gy;
            float twv = logf(w/saw + 1e-16f);
            float thv = logf(h/sah + 1e-16f);
            float px = sigf(pc[0]); acc += (px - txv)*(px - txv);
            float py = sigf(pc[1]); acc += (py - tyv)*(py - tyv);
            float dw = pc[2] - twv; acc += dw*dw;
            float dh = pc[3] - thv; acc += dh*dh;
            float pobj = sigf(pc[4]);
            acc += -clogf_(pobj);                               // obj
            acc += 0.5f*fmaxf(-log1pf(expf(pc[4])), -100.f);    // cancel noobj count at this cell
            for (int c = 0; c < CC; c++){
                float pcv = sigf(pc[5 + c]);
                acc += -((c == ci) ? clogf_(pcv) : clogf_(1.f - pcv));
            }
        }
        partial = block_reduce(acc);   // valid on thread 0
    }

    if (threadIdx.x == 0) ws[blockIdx.x] = partial;
}

// Final reduce: 1 block, 256 threads over 259 partials -> d_out[0]
__global__ void yolo_final_kernel(const float* __restrict__ ws, float* __restrict__ out){
    int t = threadIdx.x;
    float v = ws[t];
    if (t < TOTAL_BLOCKS - 256) v += ws[256 + t];
    float s = block_reduce(v);
    if (t == 0) out[0] = s;
}

extern "C" void kernel_launch(void* const* d_in, const int* in_sizes, int n_in,
                              void* d_out, int out_size, void* d_ws, size_t ws_size,
                              hipStream_t stream) {
    const float* p0      = (const float*)d_in[0];
    const float* p1      = (const float*)d_in[1];
    const float* p2      = (const float*)d_in[2];
    const float* anchors = (const float*)d_in[3];
    const float* targets = (const float*)d_in[4];
    float* out = (float*)d_out;
    float* ws  = (float*)d_ws;

    yolo_main_kernel<<<TOTAL_BLOCKS, 256, 0, stream>>>(p0, p1, p2, anchors, targets, ws);
    yolo_final_kernel<<<1, 256, 0, stream>>>(ws, out);
}